// Round 3
// baseline (141.442 us; speedup 1.0000x reference)
//
#include <hip/hip_runtime.h>

// Problem constants (from reference: clip_embeddings [32, 1024, 512] fp32)
#define BB 32
#define NN 1024
#define DD 512
#define KK 512            // k = N * 0.5
#define EPSF 1e-8f

constexpr int CH1 = 32;                    // token chunks per batch for K1/K2
constexpr int TPC = NN / CH1;              // 32 tokens per block

__device__ __forceinline__ float waveReduceSum(float v) {
#pragma unroll
    for (int m = 1; m < 64; m <<= 1) v += __shfl_xor(v, m, 64);
    return v;
}

// K1: per-token norms + unit-vector sums atomically accumulated into
// sum_unit[b][d] (zeroed by memset before launch).
// grid = BB*CH1 = 1024 blocks, 256 threads (4 waves). One wave handles one
// token at a time: 64 lanes * 8 floats = 512 = D, fully coalesced float4.
__global__ __launch_bounds__(256) void k1_norm_sum(const float* __restrict__ x,
                                                   float* __restrict__ norms,
                                                   float* __restrict__ sum_unit) {
    int blk = blockIdx.x;
    int b = blk / CH1, c = blk % CH1;
    int tid = threadIdx.x, wave = tid >> 6, lane = tid & 63;

    float4 a0 = {0.f, 0.f, 0.f, 0.f}, a1 = {0.f, 0.f, 0.f, 0.f};

    for (int t = wave; t < TPC; t += 4) {
        int n = c * TPC + t;
        const float4* p = reinterpret_cast<const float4*>(x + (size_t)(b * NN + n) * DD) + lane * 2;
        float4 v0 = p[0], v1 = p[1];
        float ssq = v0.x * v0.x + v0.y * v0.y + v0.z * v0.z + v0.w * v0.w +
                    v1.x * v1.x + v1.y * v1.y + v1.z * v1.z + v1.w * v1.w;
        ssq = waveReduceSum(ssq);
        float norm = sqrtf(ssq);
        if (lane == 0) norms[b * NN + n] = norm;
        float inv = 1.0f / fmaxf(norm, EPSF);
        a0.x += v0.x * inv; a0.y += v0.y * inv; a0.z += v0.z * inv; a0.w += v0.w * inv;
        a1.x += v1.x * inv; a1.y += v1.y * inv; a1.z += v1.z * inv; a1.w += v1.w * inv;
    }

    __shared__ float red[4][DD];
    float* r = &red[wave][lane * 8];
    r[0] = a0.x; r[1] = a0.y; r[2] = a0.z; r[3] = a0.w;
    r[4] = a1.x; r[5] = a1.y; r[6] = a1.z; r[7] = a1.w;
    __syncthreads();
#pragma unroll
    for (int i = 0; i < 2; ++i) {
        int d = tid + i * 256;
        float v = red[0][d] + red[1][d] + red[2][d] + red[3][d];
        atomicAdd(&sum_unit[b * DD + d], v);   // 32 adds/address across grid
    }
}

// K2: score[b,n] = dot(sum_unit[b], x[b,n]) / (max(norm,eps) * N)
// grid = BB*CH1 = 1024 blocks, 256 threads.
__global__ __launch_bounds__(256) void k2_scores(const float* __restrict__ x,
                                                 const float* __restrict__ norms,
                                                 const float* __restrict__ sum_unit,
                                                 float* __restrict__ scores) {
    int blk = blockIdx.x;
    int b = blk / CH1, c = blk % CH1;
    int tid = threadIdx.x, wave = tid >> 6, lane = tid & 63;

    const float4* su = reinterpret_cast<const float4*>(sum_unit + b * DD) + lane * 2;
    float4 s0 = su[0], s1 = su[1];

    for (int t = wave; t < TPC; t += 4) {
        int n = c * TPC + t;
        const float4* p = reinterpret_cast<const float4*>(x + (size_t)(b * NN + n) * DD) + lane * 2;
        float4 v0 = p[0], v1 = p[1];
        float dot = v0.x * s0.x + v0.y * s0.y + v0.z * s0.z + v0.w * s0.w +
                    v1.x * s1.x + v1.y * s1.y + v1.z * s1.z + v1.w * s1.w;
        dot = waveReduceSum(dot);
        if (lane == 0) {
            float norm = norms[b * NN + n];
            scores[b * NN + n] = dot / (fmaxf(norm, EPSF) * (float)NN);
        }
    }
}

// K34: fused select + gather. grid = BB*8 blocks, 256 threads (4 waves).
// Each block owns 128 tokens of one batch: stages the full 1024-score row in
// LDS, rank-counts its tokens (lax.top_k stable tie-break: greater, or equal
// with lower index), then gathers selected embeddings and atomically
// accumulates the scaled partial sum into out[b][*] (zeroed by memset).
__global__ __launch_bounds__(256) void k34_select_gather(const float* __restrict__ x,
                                                         const float* __restrict__ scores,
                                                         float* __restrict__ out) {
    int blk = blockIdx.x;
    int b = blk >> 3, g = blk & 7;
    int tid = threadIdx.x, wave = tid >> 6, lane = tid & 63;

    __shared__ __align__(16) float s[NN];
    __shared__ int selmask[128];
    reinterpret_cast<float4*>(s)[tid] =
        reinterpret_cast<const float4*>(scores + b * NN)[tid];   // 256*4 = 1024
    __syncthreads();

    if (tid < 128) {
        int i = g * 128 + tid;
        float my = s[i];
        int cnt = 0;
        const float4* sv = reinterpret_cast<const float4*>(s);
#pragma unroll 4
        for (int j4 = 0; j4 < NN / 4; ++j4) {
            float4 v = sv[j4];
            int j = j4 * 4;
            cnt += (v.x > my) || (v.x == my && (j + 0) < i);
            cnt += (v.y > my) || (v.y == my && (j + 1) < i);
            cnt += (v.z > my) || (v.z == my && (j + 2) < i);
            cnt += (v.w > my) || (v.w == my && (j + 3) < i);
        }
        selmask[tid] = (cnt < KK) ? 1 : 0;
    }
    __syncthreads();

    float4 a0 = {0.f, 0.f, 0.f, 0.f}, a1 = {0.f, 0.f, 0.f, 0.f};
    for (int t = wave; t < 128; t += 4) {      // wave-uniform branch per token
        if (selmask[t]) {
            int n = g * 128 + t;
            const float4* p = reinterpret_cast<const float4*>(x + (size_t)(b * NN + n) * DD) + lane * 2;
            float4 v0 = p[0], v1 = p[1];
            a0.x += v0.x; a0.y += v0.y; a0.z += v0.z; a0.w += v0.w;
            a1.x += v1.x; a1.y += v1.y; a1.z += v1.z; a1.w += v1.w;
        }
    }

    __shared__ float red[4][DD];
    float* r = &red[wave][lane * 8];
    r[0] = a0.x; r[1] = a0.y; r[2] = a0.z; r[3] = a0.w;
    r[4] = a1.x; r[5] = a1.y; r[6] = a1.z; r[7] = a1.w;
    __syncthreads();
#pragma unroll
    for (int i = 0; i < 2; ++i) {
        int d = tid + i * 256;
        float v = red[0][d] + red[1][d] + red[2][d] + red[3][d];
        atomicAdd(&out[b * DD + d], v * (1.0f / (float)KK));
    }
}

extern "C" void kernel_launch(void* const* d_in, const int* in_sizes, int n_in,
                              void* d_out, int out_size, void* d_ws, size_t ws_size,
                              hipStream_t stream) {
    const float* x = (const float*)d_in[0];
    float* out = (float*)d_out;

    float* ws = (float*)d_ws;
    float* norms    = ws;                          // B*N   = 32768 floats
    float* scores   = ws + BB * NN;                // B*N   = 32768 floats
    float* sum_unit = ws + 2 * BB * NN;            // B*D   = 16384 floats
    // total ws use: 320 KB

    hipMemsetAsync(out, 0, (size_t)BB * DD * sizeof(float), stream);
    hipMemsetAsync(sum_unit, 0, (size_t)BB * DD * sizeof(float), stream);
    k1_norm_sum<<<dim3(BB * CH1), dim3(256), 0, stream>>>(x, norms, sum_unit);
    k2_scores<<<dim3(BB * CH1), dim3(256), 0, stream>>>(x, norms, sum_unit, scores);
    k34_select_gather<<<dim3(BB * 8), dim3(256), 0, stream>>>(x, scores, out);
}

// Round 6
// 141.021 us; speedup vs baseline: 1.0030x; 1.0030x over previous
//
#include <hip/hip_runtime.h>
#include <hip/hip_cooperative_groups.h>

namespace cg = cooperative_groups;

// Problem constants (reference: clip_embeddings [32, 1024, 512] fp32)
#define BB 32
#define NN 1024
#define DD 512
#define KK 512            // k = N * 0.5
#define EPSF 1e-8f

// ---- cooperative fused kernel geometry: 1 block per CU ----
#define CBLOCKS 256       // 8 blocks per batch
#define CTHREADS 1024     // 16 waves
#define CBPB 8            // blocks per batch
#define CWAVES 16
#define TPW 8             // tokens per wave, retained in registers

__device__ __forceinline__ float wsumf(float v) {
#pragma unroll
    for (int m = 1; m < 64; m <<= 1) v += __shfl_xor(v, m, 64);
    return v;
}
__device__ __forceinline__ int wsumi(int v) {
#pragma unroll
    for (int m = 1; m < 64; m <<= 1) v += __shfl_xor(v, m, 64);
    return v;
}

// ============================ cooperative path ============================
// Reads x from HBM exactly once. Each wave owns 8 tokens: lane l holds
// x[b, n, l*8..l*8+7] in registers (16 float4/thread; all token loops fully
// unrolled -> static indexing -> registers, rule #20).
// Phase 1: norms (regs) + per-block unit-vector partials -> global ws.
// Phase 2: reduce partials -> sum_unit (LDS); scores from retained regs.
// Phase 3: stage score row in LDS; rank-count selection (lax.top_k stable
// tie-break: greater, or equal-with-lower-index); gather retained regs.
// Cross-XCD safety (Guideline 16): per-XCD L2 is writeback and NOT coherent;
// explicit __threadfence() release before and acquire after each grid.sync().
__global__ __launch_bounds__(CTHREADS, 4) void fused(const float* __restrict__ x,
                                                     float* __restrict__ partials,
                                                     float* __restrict__ scores,
                                                     float* __restrict__ out) {
    cg::grid_group grid = cg::this_grid();
    int blk = blockIdx.x;
    int b = blk >> 3, g = blk & 7;
    int tid = threadIdx.x, wave = tid >> 6, lane = tid & 63;
    int tok0 = g * 128 + wave * TPW;

    __shared__ float red[CWAVES][DD];            // 32 KB
    __shared__ __align__(16) float su_lds[DD];   // 2 KB
    __shared__ __align__(16) float s_lds[NN];    // 4 KB

    // ---- Phase 1: load x; norms; unit-sum partials ----
    float4 xs0[TPW], xs1[TPW];
    float nrm[TPW];
#pragma unroll
    for (int t = 0; t < TPW; ++t) {
        const float4* p = reinterpret_cast<const float4*>(
            x + (size_t)(b * NN + tok0 + t) * DD) + lane * 2;
        xs0[t] = p[0];
        xs1[t] = p[1];
    }
    float4 a0 = {0, 0, 0, 0}, a1 = {0, 0, 0, 0};
#pragma unroll
    for (int t = 0; t < TPW; ++t) {
        float4 v0 = xs0[t], v1 = xs1[t];
        float ssq = v0.x * v0.x + v0.y * v0.y + v0.z * v0.z + v0.w * v0.w +
                    v1.x * v1.x + v1.y * v1.y + v1.z * v1.z + v1.w * v1.w;
        ssq = wsumf(ssq);
        nrm[t] = sqrtf(ssq);
        float inv = 1.0f / fmaxf(nrm[t], EPSF);
        a0.x += v0.x * inv; a0.y += v0.y * inv; a0.z += v0.z * inv; a0.w += v0.w * inv;
        a1.x += v1.x * inv; a1.y += v1.y * inv; a1.z += v1.z * inv; a1.w += v1.w * inv;
    }
    {
        float4* rr = reinterpret_cast<float4*>(&red[wave][lane * 8]);
        rr[0] = a0; rr[1] = a1;
    }
    __syncthreads();
    if (tid < DD) {
        float s = 0.f;
#pragma unroll
        for (int w = 0; w < CWAVES; ++w) s += red[w][tid];
        partials[(size_t)blk * DD + tid] = s;    // coalesced, deterministic
    }
    __threadfence();      // release: drain partials out of this XCD's L2
    grid.sync();
    __threadfence();      // acquire: invalidate before cross-XCD reads

    // ---- Phase 2: sum_unit[b]; scores from retained registers ----
    if (tid < DD) {
        float s = 0.f;
#pragma unroll
        for (int c = 0; c < CBPB; ++c)
            s += partials[(size_t)(b * CBPB + c) * DD + tid];
        su_lds[tid] = s;
    }
    __syncthreads();
    float4 su0 = reinterpret_cast<const float4*>(&su_lds[lane * 8])[0];
    float4 su1 = reinterpret_cast<const float4*>(&su_lds[lane * 8])[1];
#pragma unroll
    for (int t = 0; t < TPW; ++t) {
        float4 v0 = xs0[t], v1 = xs1[t];
        float d = v0.x * su0.x + v0.y * su0.y + v0.z * su0.z + v0.w * su0.w +
                  v1.x * su1.x + v1.y * su1.y + v1.z * su1.z + v1.w * su1.w;
        d = wsumf(d);
        if (lane == 0)
            scores[b * NN + tok0 + t] = d / (fmaxf(nrm[t], EPSF) * (float)NN);
    }
    __threadfence();      // release scores
    grid.sync();
    __threadfence();      // acquire scores

    // ---- Phase 3: selection + gather from retained registers ----
    s_lds[tid] = scores[b * NN + tid];           // 1024 threads, full row
    __syncthreads();

    float4 c0 = {0, 0, 0, 0}, c1 = {0, 0, 0, 0};
#pragma unroll
    for (int t = 0; t < TPW; ++t) {
        int n = tok0 + t;
        float my = s_lds[n];                     // broadcast: free
        int cnt = 0;
#pragma unroll
        for (int i = 0; i < 16; ++i) {
            int j = i * 64 + lane;               // 2 lanes/bank: free
            float sj = s_lds[j];
            cnt += (sj > my) || (sj == my && j < n);
        }
        cnt = wsumi(cnt);                        // wave-uniform rank
        if (cnt < KK) {                          // wave-uniform branch
            c0.x += xs0[t].x; c0.y += xs0[t].y; c0.z += xs0[t].z; c0.w += xs0[t].w;
            c1.x += xs1[t].x; c1.y += xs1[t].y; c1.z += xs1[t].z; c1.w += xs1[t].w;
        }
    }
    {
        float4* rr = reinterpret_cast<float4*>(&red[wave][lane * 8]);
        rr[0] = c0; rr[1] = c1;
    }
    __syncthreads();
    if (tid < DD) {
        float v = 0.f;
#pragma unroll
        for (int w = 0; w < CWAVES; ++w) v += red[w][tid];
        atomicAdd(&out[b * DD + tid], v * (1.0f / (float)KK));  // 8 adds/addr
    }
}

// ======================= fallback path (R3, passed @141us) =======================
constexpr int CH1 = 32;
constexpr int TPC = NN / CH1;

__global__ __launch_bounds__(256) void k1_norm_sum(const float* __restrict__ x,
                                                   float* __restrict__ norms,
                                                   float* __restrict__ sum_unit) {
    int blk = blockIdx.x;
    int b = blk / CH1, c = blk % CH1;
    int tid = threadIdx.x, wave = tid >> 6, lane = tid & 63;
    float4 a0 = {0, 0, 0, 0}, a1 = {0, 0, 0, 0};
    for (int t = wave; t < TPC; t += 4) {
        int n = c * TPC + t;
        const float4* p = reinterpret_cast<const float4*>(x + (size_t)(b * NN + n) * DD) + lane * 2;
        float4 v0 = p[0], v1 = p[1];
        float ssq = v0.x * v0.x + v0.y * v0.y + v0.z * v0.z + v0.w * v0.w +
                    v1.x * v1.x + v1.y * v1.y + v1.z * v1.z + v1.w * v1.w;
        ssq = wsumf(ssq);
        float norm = sqrtf(ssq);
        if (lane == 0) norms[b * NN + n] = norm;
        float inv = 1.0f / fmaxf(norm, EPSF);
        a0.x += v0.x * inv; a0.y += v0.y * inv; a0.z += v0.z * inv; a0.w += v0.w * inv;
        a1.x += v1.x * inv; a1.y += v1.y * inv; a1.z += v1.z * inv; a1.w += v1.w * inv;
    }
    __shared__ float red[4][DD];
    float* r = &red[wave][lane * 8];
    r[0] = a0.x; r[1] = a0.y; r[2] = a0.z; r[3] = a0.w;
    r[4] = a1.x; r[5] = a1.y; r[6] = a1.z; r[7] = a1.w;
    __syncthreads();
#pragma unroll
    for (int i = 0; i < 2; ++i) {
        int d = tid + i * 256;
        float v = red[0][d] + red[1][d] + red[2][d] + red[3][d];
        atomicAdd(&sum_unit[b * DD + d], v);
    }
}

__global__ __launch_bounds__(256) void k2_scores(const float* __restrict__ x,
                                                 const float* __restrict__ norms,
                                                 const float* __restrict__ sum_unit,
                                                 float* __restrict__ scores) {
    int blk = blockIdx.x;
    int b = blk / CH1, c = blk % CH1;
    int tid = threadIdx.x, wave = tid >> 6, lane = tid & 63;
    const float4* su = reinterpret_cast<const float4*>(sum_unit + b * DD) + lane * 2;
    float4 s0 = su[0], s1 = su[1];
    for (int t = wave; t < TPC; t += 4) {
        int n = c * TPC + t;
        const float4* p = reinterpret_cast<const float4*>(x + (size_t)(b * NN + n) * DD) + lane * 2;
        float4 v0 = p[0], v1 = p[1];
        float dot = v0.x * s0.x + v0.y * s0.y + v0.z * s0.z + v0.w * s0.w +
                    v1.x * s1.x + v1.y * s1.y + v1.z * s1.z + v1.w * s1.w;
        dot = wsumf(dot);
        if (lane == 0) {
            float norm = norms[b * NN + n];
            scores[b * NN + n] = dot / (fmaxf(norm, EPSF) * (float)NN);
        }
    }
}

__global__ __launch_bounds__(256) void k34_select_gather(const float* __restrict__ x,
                                                         const float* __restrict__ scores,
                                                         float* __restrict__ out) {
    int blk = blockIdx.x;
    int b = blk >> 3, g = blk & 7;
    int tid = threadIdx.x, wave = tid >> 6, lane = tid & 63;
    __shared__ __align__(16) float s[NN];
    __shared__ int selmask[128];
    reinterpret_cast<float4*>(s)[tid] =
        reinterpret_cast<const float4*>(scores + b * NN)[tid];
    __syncthreads();
    if (tid < 128) {
        int i = g * 128 + tid;
        float my = s[i];
        int cnt = 0;
        const float4* sv = reinterpret_cast<const float4*>(s);
#pragma unroll 4
        for (int j4 = 0; j4 < NN / 4; ++j4) {
            float4 v = sv[j4];
            int j = j4 * 4;
            cnt += (v.x > my) || (v.x == my && (j + 0) < i);
            cnt += (v.y > my) || (v.y == my && (j + 1) < i);
            cnt += (v.z > my) || (v.z == my && (j + 2) < i);
            cnt += (v.w > my) || (v.w == my && (j + 3) < i);
        }
        selmask[tid] = (cnt < KK) ? 1 : 0;
    }
    __syncthreads();
    float4 a0 = {0, 0, 0, 0}, a1 = {0, 0, 0, 0};
    for (int t = wave; t < 128; t += 4) {
        if (selmask[t]) {
            int n = g * 128 + t;
            const float4* p = reinterpret_cast<const float4*>(x + (size_t)(b * NN + n) * DD) + lane * 2;
            float4 v0 = p[0], v1 = p[1];
            a0.x += v0.x; a0.y += v0.y; a0.z += v0.z; a0.w += v0.w;
            a1.x += v1.x; a1.y += v1.y; a1.z += v1.z; a1.w += v1.w;
        }
    }
    __shared__ float red[4][DD];
    float* r = &red[wave][lane * 8];
    r[0] = a0.x; r[1] = a0.y; r[2] = a0.z; r[3] = a0.w;
    r[4] = a1.x; r[5] = a1.y; r[6] = a1.z; r[7] = a1.w;
    __syncthreads();
#pragma unroll
    for (int i = 0; i < 2; ++i) {
        int d = tid + i * 256;
        float v = red[0][d] + red[1][d] + red[2][d] + red[3][d];
        atomicAdd(&out[b * DD + d], v * (1.0f / (float)KK));
    }
}

// ================================ launcher ================================
static void launch_fallback(const float* x, float* norms, float* sum_unit,
                            float* scores, float* out, hipStream_t stream) {
    hipMemsetAsync(sum_unit, 0, (size_t)BB * DD * sizeof(float), stream);
    k1_norm_sum<<<dim3(BB * CH1), dim3(256), 0, stream>>>(x, norms, sum_unit);
    k2_scores<<<dim3(BB * CH1), dim3(256), 0, stream>>>(x, norms, sum_unit, scores);
    k34_select_gather<<<dim3(BB * 8), dim3(256), 0, stream>>>(x, scores, out);
}

extern "C" void kernel_launch(void* const* d_in, const int* in_sizes, int n_in,
                              void* d_out, int out_size, void* d_ws, size_t ws_size,
                              hipStream_t stream) {
    const float* x = (const float*)d_in[0];
    float* out = (float*)d_out;

    float* ws = (float*)d_ws;
    float* partials = ws;                          // CBLOCKS*DD = 512 KB
    float* scores   = ws + CBLOCKS * DD;           // BB*NN = 128 KB
    float* norms    = ws + CBLOCKS * DD + BB * NN; // BB*NN (fallback only)
    float* sum_unit = norms + BB * NN;             // BB*DD (fallback only)

    // One-time host-side feasibility check (first call = uncaptured
    // correctness call; static -> identical decision every call).
    static const int coop_ok = []() {
        int nb = 0;
        hipError_t e = hipOccupancyMaxActiveBlocksPerMultiprocessor(
            &nb, reinterpret_cast<const void*>(&fused), CTHREADS, 0);
        return (e == hipSuccess && nb >= 1) ? 1 : 0;
    }();

    hipMemsetAsync(out, 0, (size_t)BB * DD * sizeof(float), stream);

    bool done = false;
    if (coop_ok) {
        void* args[] = {(void*)&x, (void*)&partials, (void*)&scores, (void*)&out};
        hipError_t le = hipLaunchCooperativeKernel((void*)fused, dim3(CBLOCKS),
                                                   dim3(CTHREADS), args, 0, stream);
        done = (le == hipSuccess);
    }
    if (!done)
        launch_fallback(x, norms, sum_unit, scores, out, stream);
}

// Round 7
// 130.779 us; speedup vs baseline: 1.0815x; 1.0783x over previous
//
#include <hip/hip_runtime.h>

// Problem constants (reference: clip_embeddings [32, 1024, 512] fp32)
#define BB 32
#define NN 1024
#define DD 512
#define KK 512            // k = N * 0.5
#define EPSF 1e-8f

#define CPB 32            // chunks (blocks) per batch for k1/k2
#define TPB 32            // tokens per block  (k1/k2)
#define TPW 8             // tokens per wave   (k1/k2)

__device__ __forceinline__ float wsumf(float v) {
#pragma unroll
    for (int m = 1; m < 64; m <<= 1) v += __shfl_xor(v, m, 64);
    return v;
}
__device__ __forceinline__ int wsumi(int v) {
#pragma unroll
    for (int m = 1; m < 64; m <<= 1) v += __shfl_xor(v, m, 64);
    return v;
}

// K1: norms + per-block unit-vector partial sums (deterministic, no atomics).
// grid = BB*CPB = 1024 blocks, 256 threads (4 waves). Each wave owns 8
// consecutive tokens; all 16 float4 loads issue up front (independent reduce
// chains -> MLP + ILP). lane l covers dims l*8..l*8+7.
__global__ __launch_bounds__(256, 4) void k1_norms_partials(const float* __restrict__ x,
                                                            float* __restrict__ norms,
                                                            float* __restrict__ partials) {
    int blk = blockIdx.x;
    int b = blk / CPB, c = blk % CPB;
    int tid = threadIdx.x, wave = tid >> 6, lane = tid & 63;
    int tok0 = c * TPB + wave * TPW;
    const float* base = x + (size_t)(b * NN + tok0) * DD;

    float4 xs0[TPW], xs1[TPW];
#pragma unroll
    for (int t = 0; t < TPW; ++t) {
        const float4* p = reinterpret_cast<const float4*>(base + (size_t)t * DD) + lane * 2;
        xs0[t] = p[0];
        xs1[t] = p[1];
    }

    float4 a0 = {0, 0, 0, 0}, a1 = {0, 0, 0, 0};
#pragma unroll
    for (int t = 0; t < TPW; ++t) {
        float4 v0 = xs0[t], v1 = xs1[t];
        float ssq = v0.x * v0.x + v0.y * v0.y + v0.z * v0.z + v0.w * v0.w +
                    v1.x * v1.x + v1.y * v1.y + v1.z * v1.z + v1.w * v1.w;
        ssq = wsumf(ssq);
        float nrm = sqrtf(ssq);
        if (lane == 0) norms[b * NN + tok0 + t] = nrm;
        float inv = 1.0f / fmaxf(nrm, EPSF);
        a0.x += v0.x * inv; a0.y += v0.y * inv; a0.z += v0.z * inv; a0.w += v0.w * inv;
        a1.x += v1.x * inv; a1.y += v1.y * inv; a1.z += v1.z * inv; a1.w += v1.w * inv;
    }

    __shared__ float red[4][DD];
    {
        float4* rr = reinterpret_cast<float4*>(&red[wave][lane * 8]);
        rr[0] = a0; rr[1] = a1;
    }
    __syncthreads();
#pragma unroll
    for (int i = 0; i < 2; ++i) {
        int d = tid + i * 256;
        partials[(size_t)blk * DD + d] = red[0][d] + red[1][d] + red[2][d] + red[3][d];
    }
}

// K2: per-block deterministic reduce of the batch's 32 partials -> sum_unit
// (LDS only), then scores for this block's 32 tokens from L3-resident x.
// Blocks with c==0 also zero out[b] (runs before k34 by stream order).
// score[b,n] = dot(sum_unit, x_n) / (max(norm_n, eps) * N)
__global__ __launch_bounds__(256, 4) void k2_scores(const float* __restrict__ x,
                                                    const float* __restrict__ norms,
                                                    const float* __restrict__ partials,
                                                    float* __restrict__ scores,
                                                    float* __restrict__ out) {
    int blk = blockIdx.x;
    int b = blk / CPB, c = blk % CPB;
    int tid = threadIdx.x, wave = tid >> 6, lane = tid & 63;

    __shared__ __align__(16) float su_lds[DD];
    {
        float s0 = 0.f, s1 = 0.f;
        const float* pb = partials + (size_t)b * CPB * DD;
#pragma unroll
        for (int cc = 0; cc < CPB; ++cc) {          // fixed order: deterministic
            s0 += pb[(size_t)cc * DD + tid];
            s1 += pb[(size_t)cc * DD + tid + 256];
        }
        su_lds[tid] = s0;
        su_lds[tid + 256] = s1;
    }
    if (c == 0) {                                    // zero out[b] for k34
        out[b * DD + tid] = 0.f;
        out[b * DD + tid + 256] = 0.f;
    }
    __syncthreads();

    float4 su0 = reinterpret_cast<const float4*>(&su_lds[lane * 8])[0];
    float4 su1 = reinterpret_cast<const float4*>(&su_lds[lane * 8])[1];

    int tok0 = c * TPB + wave * TPW;
    const float* base = x + (size_t)(b * NN + tok0) * DD;
#pragma unroll
    for (int t = 0; t < TPW; ++t) {
        const float4* p = reinterpret_cast<const float4*>(base + (size_t)t * DD) + lane * 2;
        float4 v0 = p[0], v1 = p[1];
        float d = v0.x * su0.x + v0.y * su0.y + v0.z * su0.z + v0.w * su0.w +
                  v1.x * su1.x + v1.y * su1.y + v1.z * su1.z + v1.w * su1.w;
        d = wsumf(d);
        if (lane == 0) {
            float nrm = norms[b * NN + tok0 + t];
            scores[b * NN + tok0 + t] = d / (fmaxf(nrm, EPSF) * (float)NN);
        }
    }
}

// K34: fused rank-count selection + gather. grid = BB*8 blocks, 256 threads
// (4 waves, 32 tokens/wave -> 128 tokens/block). Rank-count reproduces
// lax.top_k's stable tie-break (greater, or equal with lower index); the
// count is wave-parallel (each lane covers 16 of 1024 scores via float4 LDS
// reads, then wsumi). Selected tokens' embeddings accumulate from L3-resident
// x; block reduce; 8 atomicAdds per out element (out zeroed by k2).
__global__ __launch_bounds__(256, 4) void k34_select_gather(const float* __restrict__ x,
                                                            const float* __restrict__ scores,
                                                            float* __restrict__ out) {
    int blk = blockIdx.x;
    int b = blk >> 3, g = blk & 7;
    int tid = threadIdx.x, wave = tid >> 6, lane = tid & 63;

    __shared__ __align__(16) float s_lds[NN];
    reinterpret_cast<float4*>(s_lds)[tid] =
        reinterpret_cast<const float4*>(scores + b * NN)[tid];   // 256*4 = 1024
    __syncthreads();

    const float4* sv = reinterpret_cast<const float4*>(s_lds);
    float4 c0 = {0, 0, 0, 0}, c1 = {0, 0, 0, 0};
    int tok0 = g * 128 + wave * 32;

#pragma unroll 4
    for (int t = 0; t < 32; ++t) {
        int n = tok0 + t;
        float my = s_lds[n];                          // broadcast: free
        int cnt = 0;
#pragma unroll
        for (int i = 0; i < 4; ++i) {
            int j4 = i * 64 + lane;                   // conflict-free b128 reads
            float4 v = sv[j4];
            int j = j4 * 4;
            cnt += (v.x > my) || (v.x == my && (j + 0) < n);
            cnt += (v.y > my) || (v.y == my && (j + 1) < n);
            cnt += (v.z > my) || (v.z == my && (j + 2) < n);
            cnt += (v.w > my) || (v.w == my && (j + 3) < n);
        }
        cnt = wsumi(cnt);                             // wave-uniform rank
        if (cnt < KK) {                               // wave-uniform branch
            const float4* p = reinterpret_cast<const float4*>(
                x + (size_t)(b * NN + n) * DD) + lane * 2;
            float4 v0 = p[0], v1 = p[1];
            c0.x += v0.x; c0.y += v0.y; c0.z += v0.z; c0.w += v0.w;
            c1.x += v1.x; c1.y += v1.y; c1.z += v1.z; c1.w += v1.w;
        }
    }

    __shared__ float red[4][DD];
    {
        float4* rr = reinterpret_cast<float4*>(&red[wave][lane * 8]);
        rr[0] = c0; rr[1] = c1;
    }
    __syncthreads();
#pragma unroll
    for (int i = 0; i < 2; ++i) {
        int d = tid + i * 256;
        float v = red[0][d] + red[1][d] + red[2][d] + red[3][d];
        atomicAdd(&out[b * DD + d], v * (1.0f / (float)KK));   // 8 adds/addr
    }
}

extern "C" void kernel_launch(void* const* d_in, const int* in_sizes, int n_in,
                              void* d_out, int out_size, void* d_ws, size_t ws_size,
                              hipStream_t stream) {
    const float* x = (const float*)d_in[0];
    float* out = (float*)d_out;

    float* ws = (float*)d_ws;
    float* partials = ws;                               // 1024*512 = 2 MB
    float* scores   = ws + BB * CPB * DD;               // BB*NN = 128 KB
    float* norms    = ws + BB * CPB * DD + BB * NN;     // BB*NN = 128 KB

    k1_norms_partials<<<dim3(BB * CPB), dim3(256), 0, stream>>>(x, norms, partials);
    k2_scores<<<dim3(BB * CPB), dim3(256), 0, stream>>>(x, norms, partials, scores, out);
    k34_select_gather<<<dim3(BB * 8), dim3(256), 0, stream>>>(x, scores, out);
}

// Round 8
// 130.749 us; speedup vs baseline: 1.0818x; 1.0002x over previous
//
#include <hip/hip_runtime.h>
#include <hip/hip_cooperative_groups.h>

namespace cg = cooperative_groups;

// Problem constants (reference: clip_embeddings [32, 1024, 512] fp32)
#define BB 32
#define NN 1024
#define DD 512
#define KK 512            // k = N * 0.5
#define EPSF 1e-8f

#define BLOCKS 1024       // 4 blocks/CU on 256 CUs (coop co-residency)
#define THREADS 256       // 4 waves
#define CPB 32            // blocks per batch
#define TPB 32            // tokens per block
#define TPW 8             // tokens per wave

__device__ __forceinline__ float wsumf(float v) {
#pragma unroll
    for (int m = 1; m < 64; m <<= 1) v += __shfl_xor(v, m, 64);
    return v;
}
__device__ __forceinline__ int wsumi(int v) {
#pragma unroll
    for (int m = 1; m < 64; m <<= 1) v += __shfl_xor(v, m, 64);
    return v;
}

// ===================== single cooperative kernel (3 phases) =====================
// NOTHING is retained in registers across grid.sync() (R6 lesson: retention ->
// scratch spills). Phase 2 reloads x from L3; norms cross phases via LDS.
// Phase 1: read x (HBM, once), per-token norms -> LDS, per-block unit-vector
//          partial sums -> global ws (deterministic, no atomics).
// Phase 2: redundant per-block reduce of batch partials -> sum_unit (LDS);
//          scores for this block's 32 tokens from L3-resident x; c==0 blocks
//          zero out[b].
// Phase 3: stage batch score row in LDS; rank-count selection (lax.top_k
//          stable tie-break: greater, or equal-with-lower-index); gather
//          selected tokens from L3; block reduce; atomicAdd into out.
// Cross-XCD safety (Guideline 16): release fence before / acquire fence after
// each grid.sync() — pattern correctness-proven in R6.
__global__ __launch_bounds__(THREADS, 4) void fused3(const float* __restrict__ x,
                                                     float* __restrict__ partials,
                                                     float* __restrict__ scores,
                                                     float* __restrict__ out) {
    cg::grid_group grid = cg::this_grid();
    int blk = blockIdx.x;
    int b = blk / CPB, c = blk % CPB;
    int tid = threadIdx.x, wave = tid >> 6, lane = tid & 63;
    int tok0 = c * TPB + wave * TPW;
    const float* base = x + (size_t)(b * NN + tok0) * DD;

    __shared__ float red[4][DD];                 // 8 KB (reused ph1/ph3)
    __shared__ __align__(16) float su_lds[DD];   // 2 KB
    __shared__ __align__(16) float s_lds[NN];    // 4 KB
    __shared__ float nrm_lds[TPB];               // 128 B (persists ph1 -> ph2)

    // ---------------- Phase 1: norms + unit-sum partials ----------------
    {
        float4 xs0[TPW], xs1[TPW];
#pragma unroll
        for (int t = 0; t < TPW; ++t) {
            const float4* p = reinterpret_cast<const float4*>(base + (size_t)t * DD) + lane * 2;
            xs0[t] = p[0];
            xs1[t] = p[1];
        }
        float4 a0 = {0, 0, 0, 0}, a1 = {0, 0, 0, 0};
#pragma unroll
        for (int t = 0; t < TPW; ++t) {
            float4 v0 = xs0[t], v1 = xs1[t];
            float ssq = v0.x * v0.x + v0.y * v0.y + v0.z * v0.z + v0.w * v0.w +
                        v1.x * v1.x + v1.y * v1.y + v1.z * v1.z + v1.w * v1.w;
            ssq = wsumf(ssq);
            float nrm = sqrtf(ssq);
            if (lane == 0) nrm_lds[wave * TPW + t] = nrm;
            float inv = 1.0f / fmaxf(nrm, EPSF);
            a0.x += v0.x * inv; a0.y += v0.y * inv; a0.z += v0.z * inv; a0.w += v0.w * inv;
            a1.x += v1.x * inv; a1.y += v1.y * inv; a1.z += v1.z * inv; a1.w += v1.w * inv;
        }
        float4* rr = reinterpret_cast<float4*>(&red[wave][lane * 8]);
        rr[0] = a0; rr[1] = a1;
    }
    __syncthreads();
#pragma unroll
    for (int i = 0; i < 2; ++i) {
        int d = tid + i * 256;
        partials[(size_t)blk * DD + d] = red[0][d] + red[1][d] + red[2][d] + red[3][d];
    }
    __threadfence();      // release partials past this XCD's L2
    grid.sync();
    __threadfence();      // acquire before cross-XCD reads

    // ---------------- Phase 2: sum_unit + scores ----------------
    {
        float s0 = 0.f, s1 = 0.f;
        const float* pb = partials + (size_t)b * CPB * DD;
#pragma unroll
        for (int cc = 0; cc < CPB; ++cc) {       // fixed order: deterministic
            s0 += pb[(size_t)cc * DD + tid];
            s1 += pb[(size_t)cc * DD + tid + 256];
        }
        su_lds[tid] = s0;
        su_lds[tid + 256] = s1;
    }
    if (c == 0) {                                 // zero out[b] before ph3 atomics
        out[b * DD + tid] = 0.f;
        out[b * DD + tid + 256] = 0.f;
    }
    __syncthreads();
    {
        float4 su0 = reinterpret_cast<const float4*>(&su_lds[lane * 8])[0];
        float4 su1 = reinterpret_cast<const float4*>(&su_lds[lane * 8])[1];
#pragma unroll
        for (int t = 0; t < TPW; ++t) {           // x reload: L3-resident
            const float4* p = reinterpret_cast<const float4*>(base + (size_t)t * DD) + lane * 2;
            float4 v0 = p[0], v1 = p[1];
            float d = v0.x * su0.x + v0.y * su0.y + v0.z * su0.z + v0.w * su0.w +
                      v1.x * su1.x + v1.y * su1.y + v1.z * su1.z + v1.w * su1.w;
            d = wsumf(d);
            if (lane == 0) {
                float nrm = nrm_lds[wave * TPW + t];
                scores[b * NN + tok0 + t] = d / (fmaxf(nrm, EPSF) * (float)NN);
            }
        }
    }
    __threadfence();      // release scores
    grid.sync();
    __threadfence();      // acquire scores

    // ---------------- Phase 3: selection + gather ----------------
    reinterpret_cast<float4*>(s_lds)[tid] =
        reinterpret_cast<const float4*>(scores + b * NN)[tid];   // 256*4 = 1024
    __syncthreads();

    const float4* sv = reinterpret_cast<const float4*>(s_lds);
    float4 c0 = {0, 0, 0, 0}, c1 = {0, 0, 0, 0};
#pragma unroll
    for (int t = 0; t < TPW; ++t) {
        int n = tok0 + t;
        float my = s_lds[n];                      // broadcast: free
        int cnt = 0;
#pragma unroll
        for (int i = 0; i < 4; ++i) {
            int j4 = i * 64 + lane;               // 2 lanes/bank: free
            float4 v = sv[j4];
            int j = j4 * 4;
            cnt += (v.x > my) || (v.x == my && (j + 0) < n);
            cnt += (v.y > my) || (v.y == my && (j + 1) < n);
            cnt += (v.z > my) || (v.z == my && (j + 2) < n);
            cnt += (v.w > my) || (v.w == my && (j + 3) < n);
        }
        cnt = wsumi(cnt);                         // wave-uniform rank
        if (cnt < KK) {                           // wave-uniform branch
            const float4* p = reinterpret_cast<const float4*>(base + (size_t)t * DD) + lane * 2;
            float4 v0 = p[0], v1 = p[1];
            c0.x += v0.x; c0.y += v0.y; c0.z += v0.z; c0.w += v0.w;
            c1.x += v1.x; c1.y += v1.y; c1.z += v1.z; c1.w += v1.w;
        }
    }
    {
        float4* rr = reinterpret_cast<float4*>(&red[wave][lane * 8]);
        rr[0] = c0; rr[1] = c1;
    }
    __syncthreads();
#pragma unroll
    for (int i = 0; i < 2; ++i) {
        int d = tid + i * 256;
        float v = red[0][d] + red[1][d] + red[2][d] + red[3][d];
        atomicAdd(&out[b * DD + d], v * (1.0f / (float)KK));   // 32 adds/addr
    }
}

// ===================== fallback: R7 3-kernel pipeline (passed @130.8) =====================
__global__ __launch_bounds__(256, 4) void k1_norms_partials(const float* __restrict__ x,
                                                            float* __restrict__ norms,
                                                            float* __restrict__ partials) {
    int blk = blockIdx.x;
    int b = blk / CPB, c = blk % CPB;
    int tid = threadIdx.x, wave = tid >> 6, lane = tid & 63;
    int tok0 = c * TPB + wave * TPW;
    const float* base = x + (size_t)(b * NN + tok0) * DD;
    float4 xs0[TPW], xs1[TPW];
#pragma unroll
    for (int t = 0; t < TPW; ++t) {
        const float4* p = reinterpret_cast<const float4*>(base + (size_t)t * DD) + lane * 2;
        xs0[t] = p[0];
        xs1[t] = p[1];
    }
    float4 a0 = {0, 0, 0, 0}, a1 = {0, 0, 0, 0};
#pragma unroll
    for (int t = 0; t < TPW; ++t) {
        float4 v0 = xs0[t], v1 = xs1[t];
        float ssq = v0.x * v0.x + v0.y * v0.y + v0.z * v0.z + v0.w * v0.w +
                    v1.x * v1.x + v1.y * v1.y + v1.z * v1.z + v1.w * v1.w;
        ssq = wsumf(ssq);
        float nrm = sqrtf(ssq);
        if (lane == 0) norms[b * NN + tok0 + t] = nrm;
        float inv = 1.0f / fmaxf(nrm, EPSF);
        a0.x += v0.x * inv; a0.y += v0.y * inv; a0.z += v0.z * inv; a0.w += v0.w * inv;
        a1.x += v1.x * inv; a1.y += v1.y * inv; a1.z += v1.z * inv; a1.w += v1.w * inv;
    }
    __shared__ float red[4][DD];
    {
        float4* rr = reinterpret_cast<float4*>(&red[wave][lane * 8]);
        rr[0] = a0; rr[1] = a1;
    }
    __syncthreads();
#pragma unroll
    for (int i = 0; i < 2; ++i) {
        int d = tid + i * 256;
        partials[(size_t)blk * DD + d] = red[0][d] + red[1][d] + red[2][d] + red[3][d];
    }
}

__global__ __launch_bounds__(256, 4) void k2_scores(const float* __restrict__ x,
                                                    const float* __restrict__ norms,
                                                    const float* __restrict__ partials,
                                                    float* __restrict__ scores,
                                                    float* __restrict__ out) {
    int blk = blockIdx.x;
    int b = blk / CPB, c = blk % CPB;
    int tid = threadIdx.x, wave = tid >> 6, lane = tid & 63;
    __shared__ __align__(16) float su_lds[DD];
    {
        float s0 = 0.f, s1 = 0.f;
        const float* pb = partials + (size_t)b * CPB * DD;
#pragma unroll
        for (int cc = 0; cc < CPB; ++cc) {
            s0 += pb[(size_t)cc * DD + tid];
            s1 += pb[(size_t)cc * DD + tid + 256];
        }
        su_lds[tid] = s0;
        su_lds[tid + 256] = s1;
    }
    if (c == 0) {
        out[b * DD + tid] = 0.f;
        out[b * DD + tid + 256] = 0.f;
    }
    __syncthreads();
    float4 su0 = reinterpret_cast<const float4*>(&su_lds[lane * 8])[0];
    float4 su1 = reinterpret_cast<const float4*>(&su_lds[lane * 8])[1];
    int tok0 = c * TPB + wave * TPW;
    const float* base = x + (size_t)(b * NN + tok0) * DD;
#pragma unroll
    for (int t = 0; t < TPW; ++t) {
        const float4* p = reinterpret_cast<const float4*>(base + (size_t)t * DD) + lane * 2;
        float4 v0 = p[0], v1 = p[1];
        float d = v0.x * su0.x + v0.y * su0.y + v0.z * su0.z + v0.w * su0.w +
                  v1.x * su1.x + v1.y * su1.y + v1.z * su1.z + v1.w * su1.w;
        d = wsumf(d);
        if (lane == 0) {
            float nrm = norms[b * NN + tok0 + t];
            scores[b * NN + tok0 + t] = d / (fmaxf(nrm, EPSF) * (float)NN);
        }
    }
}

__global__ __launch_bounds__(256, 4) void k34_select_gather(const float* __restrict__ x,
                                                            const float* __restrict__ scores,
                                                            float* __restrict__ out) {
    int blk = blockIdx.x;
    int b = blk >> 3, g = blk & 7;
    int tid = threadIdx.x, wave = tid >> 6, lane = tid & 63;
    __shared__ __align__(16) float s_lds[NN];
    reinterpret_cast<float4*>(s_lds)[tid] =
        reinterpret_cast<const float4*>(scores + b * NN)[tid];
    __syncthreads();
    const float4* sv = reinterpret_cast<const float4*>(s_lds);
    float4 c0 = {0, 0, 0, 0}, c1 = {0, 0, 0, 0};
    int tok0 = g * 128 + wave * 32;
#pragma unroll 4
    for (int t = 0; t < 32; ++t) {
        int n = tok0 + t;
        float my = s_lds[n];
        int cnt = 0;
#pragma unroll
        for (int i = 0; i < 4; ++i) {
            int j4 = i * 64 + lane;
            float4 v = sv[j4];
            int j = j4 * 4;
            cnt += (v.x > my) || (v.x == my && (j + 0) < n);
            cnt += (v.y > my) || (v.y == my && (j + 1) < n);
            cnt += (v.z > my) || (v.z == my && (j + 2) < n);
            cnt += (v.w > my) || (v.w == my && (j + 3) < n);
        }
        cnt = wsumi(cnt);
        if (cnt < KK) {
            const float4* p = reinterpret_cast<const float4*>(
                x + (size_t)(b * NN + n) * DD) + lane * 2;
            float4 v0 = p[0], v1 = p[1];
            c0.x += v0.x; c0.y += v0.y; c0.z += v0.z; c0.w += v0.w;
            c1.x += v1.x; c1.y += v1.y; c1.z += v1.z; c1.w += v1.w;
        }
    }
    __shared__ float red[4][DD];
    {
        float4* rr = reinterpret_cast<float4*>(&red[wave][lane * 8]);
        rr[0] = c0; rr[1] = c1;
    }
    __syncthreads();
#pragma unroll
    for (int i = 0; i < 2; ++i) {
        int d = tid + i * 256;
        float v = red[0][d] + red[1][d] + red[2][d] + red[3][d];
        atomicAdd(&out[b * DD + d], v * (1.0f / (float)KK));
    }
}

// ================================ launcher ================================
extern "C" void kernel_launch(void* const* d_in, const int* in_sizes, int n_in,
                              void* d_out, int out_size, void* d_ws, size_t ws_size,
                              hipStream_t stream) {
    const float* x = (const float*)d_in[0];
    float* out = (float*)d_out;

    float* ws = (float*)d_ws;
    float* partials = ws;                               // 1024*512 = 2 MB
    float* scores   = ws + BLOCKS * DD;                 // BB*NN = 128 KB
    float* norms    = ws + BLOCKS * DD + BB * NN;       // BB*NN (fallback only)

    // One-time host-side co-residency check (first call = uncaptured
    // correctness call; static -> identical node set for graph capture).
    static const int coop_ok = []() {
        int nb = 0;
        hipError_t e = hipOccupancyMaxActiveBlocksPerMultiprocessor(
            &nb, reinterpret_cast<const void*>(&fused3), THREADS, 0);
        return (e == hipSuccess && nb >= BLOCKS / 256) ? 1 : 0;   // need 4/CU
    }();

    bool done = false;
    if (coop_ok) {
        void* args[] = {(void*)&x, (void*)&partials, (void*)&scores, (void*)&out};
        hipError_t le = hipLaunchCooperativeKernel((void*)fused3, dim3(BLOCKS),
                                                   dim3(THREADS), args, 0, stream);
        done = (le == hipSuccess);
    }
    if (!done) {
        k1_norms_partials<<<dim3(BB * CPB), dim3(256), 0, stream>>>(x, norms, partials);
        k2_scores<<<dim3(BB * CPB), dim3(256), 0, stream>>>(x, norms, partials, scores, out);
        k34_select_gather<<<dim3(BB * 8), dim3(256), 0, stream>>>(x, scores, out);
    }
}